// Round 16
// baseline (220.378 us; speedup 1.0000x reference)
//
#include <hip/hip_runtime.h>
#include <stdint.h>

#define H 16
#define DH 64
#define T 2048
#define SS 2048
#define L 4096
#define DIM 1024
#define BB 2

typedef __bf16 bf16x8 __attribute__((ext_vector_type(8)));
typedef float f32x4 __attribute__((ext_vector_type(4)));
typedef float f32x16 __attribute__((ext_vector_type(16)));
typedef unsigned u32x4 __attribute__((ext_vector_type(4)));

__device__ __forceinline__ unsigned short f2bf(float f){
  unsigned u = __builtin_bit_cast(unsigned, f);
  u += 0x7fff + ((u >> 16) & 1);
  return (unsigned short)(u >> 16);
}

__device__ __forceinline__ unsigned cvt_pk_bf16(float lo, float hi){
  unsigned r;
  asm("v_cvt_pk_bf16_f32 %0, %1, %2" : "=v"(r) : "v"(lo), "v"(hi));
  return r;
}

__device__ __forceinline__ float fmax3(float a, float b, float c){
  float r;
  asm("v_max3_f32 %0, %1, %2, %3" : "=v"(r) : "v"(a), "v"(b), "v"(c));
  return r;
}

__device__ __forceinline__ void gload_lds16(const void* g, void* l){
  void* gnc = const_cast<void*>(g);
  __builtin_amdgcn_global_load_lds((__attribute__((address_space(1))) void*)gnc,
                                   (__attribute__((address_space(3))) void*)l, 16, 0, 0);
}

// ---------------- LayerNorm (x rows then ctx rows) -> bf16 ----------------
__global__ __launch_bounds__(256) void ln_kernel(const float* __restrict__ x, const float* __restrict__ ctx,
                          const float* __restrict__ g, const float* __restrict__ b,
                          unsigned short* __restrict__ out){
  int row = blockIdx.x;
  int tid = threadIdx.x;
  const float* src = (row < BB*T) ? (x + (size_t)row*DIM) : (ctx + (size_t)(row - BB*T)*DIM);
  float4 v = reinterpret_cast<const float4*>(src)[tid];
  float s  = v.x + v.y + v.z + v.w;
  float s2 = v.x*v.x + v.y*v.y + v.z*v.z + v.w*v.w;
  #pragma unroll
  for (int off = 32; off > 0; off >>= 1){
    s  += __shfl_down(s,  off, 64);
    s2 += __shfl_down(s2, off, 64);
  }
  __shared__ float red[8];
  if ((tid & 63) == 0){ red[(tid>>6)*2] = s; red[(tid>>6)*2+1] = s2; }
  __syncthreads();
  s  = red[0] + red[2] + red[4] + red[6];
  s2 = red[1] + red[3] + red[5] + red[7];
  float mean = s * (1.0f/DIM);
  float var  = s2 * (1.0f/DIM) - mean*mean;
  float rstd = rsqrtf(var + 1e-5f);
  float4 gg = reinterpret_cast<const float4*>(g)[tid];
  float4 bv = reinterpret_cast<const float4*>(b)[tid];
  ushort4 o;
  o.x = f2bf((v.x-mean)*rstd*gg.x + bv.x);
  o.y = f2bf((v.y-mean)*rstd*gg.y + bv.y);
  o.z = f2bf((v.z-mean)*rstd*gg.z + bv.z);
  o.w = f2bf((v.w-mean)*rstd*gg.w + bv.w);
  reinterpret_cast<ushort4*>(out + (size_t)row*DIM)[tid] = o;
}

// ---------------- transpose fp32 [R][C] -> bf16 [C][R] ----------------
__global__ __launch_bounds__(256) void transpose_f32_bf16(const float* __restrict__ in,
                          unsigned short* __restrict__ out, int R, int C){
  __shared__ float tile[32][33];
  int c0 = blockIdx.x*32, r0 = blockIdx.y*32;
  int tx = threadIdx.x & 31, ty = threadIdx.x >> 5;
  #pragma unroll
  for (int k = 0; k < 4; k++)
    tile[ty + k*8][tx] = in[(size_t)(r0 + ty + k*8)*C + c0 + tx];
  __syncthreads();
  #pragma unroll
  for (int k = 0; k < 4; k++)
    out[(size_t)(c0 + ty + k*8)*R + r0 + tx] = f2bf(tile[tx][ty + k*8]);
}

// ---------------- QKV GEMM: 256x256 tile, phase-interleaved K-loop (T3+T4+T5) --------------
// 512 thr = 8 waves (2M x 4N), per-wave C = 128x64.  BK=64, 16 K-tile iters, strict LDS
// double-buffer (128KB): buf d read in iter j (d=j&1), written in iter j+1 with next K-tile.
// Per iter: 4 quadrant phases {12 ds_read | prefetch issued in phases 0-1 | barrier |
// setprio+16 MFMA | barrier}; ONE vmcnt(0) per iter at phase 3 (issues have ~2 phases of
// slack, unlike the 2-phase drain-per-step structure).  Staging swizzle c16^=(row&7) via
// pre-swizzled global source -> conflict-free ds_read_b128.  320 active tiles, XCD-contig
// a-range, m fastest (B panel L2-hot).
__global__ __launch_bounds__(512, 2) void qkv_gemm(const unsigned short* __restrict__ A,
      const unsigned short* __restrict__ Bt, const float* __restrict__ bias,
      unsigned short* __restrict__ qbuf, unsigned short* __restrict__ kbuf,
      unsigned short* __restrict__ vtbuf){
  int g = blockIdx.x;
  int a_ = (g >> 3) + 40*(g & 7);        // 40 contiguous tiles per XCD, m fastest
  int m_, n_;
  if (a_ < 64){ n_ = a_ >> 4; m_ = a_ & 15; }            // Q n-tiles: x rows only
  else        { int a2 = a_ - 64; n_ = 4 + (a2 >> 5); m_ = a2 & 31; }
  int n0 = n_*256, m0 = m_*256;
  __shared__ union {
    struct { unsigned short a[2][2][128*64]; unsigned short b[2][2][128*64]; } s;  // 128 KB
    unsigned short ct[128][264];   // Q/K epilogue, 2 passes over m-halves
    unsigned short vt[256][136];   // V epilogue, 2 passes over m-halves
  } u;
  int tid = threadIdx.x, lane = tid & 63, wv = tid >> 6;
  int l15 = lane & 15, g4 = lane >> 4;
  int wr = wv >> 2, wc = wv & 3;

  f32x4 acc[8][4];
  #pragma unroll
  for (int i = 0; i < 8; i++)
    #pragma unroll
    for (int j = 0; j < 4; j++) acc[i][j] = (f32x4){0.f,0.f,0.f,0.f};

  // stage one half-tile (128 rows x 64 k) of K-tile jt into dbuf dd (2 gloads/thread)
  #define QS_HT(dd, isB, half, jt) { \
    const unsigned short* _s = (isB) ? Bt : A; \
    int _b0 = ((isB) ? n0 : m0) + (half)*128; \
    unsigned short* _d = (isB) ? &u.s.b[dd][half][0] : &u.s.a[dd][half][0]; \
    _Pragma("unroll") \
    for (int _j = 0; _j < 2; _j++){ \
      int _i = _j*512 + tid, _r = _i >> 3, _c = (_i & 7) ^ (_r & 7); \
      gload_lds16((const char*)_s + ((size_t)(_b0 + _r)*DIM + (jt)*64)*2 + _c*16, \
                  (char*)_d + (_j*512 + wv*64)*16); \
    } }

  QS_HT(0,0,0,0); QS_HT(0,0,1,0); QS_HT(0,1,0,0); QS_HT(0,1,1,0);
  __syncthreads();

  for (int jt = 0; jt < 16; ++jt){
    int d = jt & 1;
    const char* ab = (const char*)&u.s.a[d][0][0];   // flat [256 rows][64 k]
    const char* bb = (const char*)&u.s.b[d][0][0];   // flat [256 cols][64 k]
    #pragma unroll
    for (int q = 0; q < 4; q++){
      int mq = (q >> 1)*4, nq = (q & 1)*2;
      bf16x8 af[4][2], bfr[2][2];
      #pragma unroll
      for (int i2 = 0; i2 < 4; i2++){
        int ar = wr*128 + (mq + i2)*16 + l15;
        #pragma unroll
        for (int kk = 0; kk < 2; kk++)
          af[i2][kk] = *reinterpret_cast<const bf16x8*>(ab + (size_t)ar*128 + (((kk*4 + g4) ^ (ar & 7))*16));
      }
      #pragma unroll
      for (int nj = 0; nj < 2; nj++){
        int bc = wc*64 + (nq + nj)*16 + l15;
        #pragma unroll
        for (int kk = 0; kk < 2; kk++)
          bfr[nj][kk] = *reinterpret_cast<const bf16x8*>(bb + (size_t)bc*128 + (((kk*4 + g4) ^ (bc & 7))*16));
      }
      if (jt < 15){
        if (q == 0){ QS_HT(d^1, 0, 0, jt+1); QS_HT(d^1, 0, 1, jt+1); }
        if (q == 1){ QS_HT(d^1, 1, 0, jt+1); QS_HT(d^1, 1, 1, jt+1); }
      }
      __builtin_amdgcn_s_barrier();
      __builtin_amdgcn_s_setprio(1);
      #pragma unroll
      for (int kk = 0; kk < 2; kk++)
        #pragma unroll
        for (int i2 = 0; i2 < 4; i2++)
          #pragma unroll
          for (int nj = 0; nj < 2; nj++)
            acc[mq+i2][nq+nj] = __builtin_amdgcn_mfma_f32_16x16x32_bf16(af[i2][kk], bfr[nj][kk], acc[mq+i2][nq+nj], 0,0,0);
      __builtin_amdgcn_s_setprio(0);
      if (q == 3) asm volatile("s_waitcnt vmcnt(0)" ::: "memory");
      __builtin_amdgcn_s_barrier();
    }
  }
  __syncthreads();

  int sec = n0 >> 10;   // 0=Q, 1=K, 2=V  (256 | 1024 -> no tile straddles)
  if (sec < 2){
    float scale = (sec == 0) ? 0.18033688f : 1.0f;  // 0.125*log2(e) for Q
    #pragma unroll
    for (int p = 0; p < 2; p++){
      __syncthreads();
      if (wr == p){
        #pragma unroll
        for (int ni = 0; ni < 4; ni++){
          int nl = wc*64 + ni*16 + l15;
          float bv = bias[n0 + nl];
          #pragma unroll
          for (int mi = 0; mi < 8; mi++){
            int mloc = mi*16 + (g4 << 2);
            #pragma unroll
            for (int r = 0; r < 4; r++)
              u.ct[mloc + r][nl] = f2bf((acc[mi][ni][r] + bv)*scale);
          }
        }
      }
      __syncthreads();
      #pragma unroll
      for (int c = 0; c < 8; c++){
        int idx = c*512 + tid;
        int row = idx >> 5, ch = idx & 31;
        bf16x8 v = *reinterpret_cast<const bf16x8*>(&u.ct[row][ch*8]);
        int gm = m0 + p*128 + row, gn = n0 + ch*8;
        int cc = gn & 1023, hh2 = cc >> 6, dd = cc & 63;
        bool isctx = gm >= BB*T;
        int rm = isctx ? gm - BB*T : gm;
        int bidx = rm >> 11, tt = rm & 2047;
        size_t bh2 = (size_t)bidx*H + hh2;
        if (sec == 0){
          *reinterpret_cast<bf16x8*>(qbuf + (bh2*T + tt)*DH + dd) = v;   // Q tiles never ctx
        } else {
          int j = isctx ? T + tt : tt;
          *reinterpret_cast<bf16x8*>(kbuf + (bh2*L + j)*DH + dd) = v;
        }
      }
    }
  } else {
    #pragma unroll
    for (int p = 0; p < 2; p++){
      __syncthreads();
      if (wr == p){
        #pragma unroll
        for (int ni = 0; ni < 4; ni++){
          int nl = wc*64 + ni*16 + l15;
          float bv = bias[n0 + nl];
          #pragma unroll
          for (int mi = 0; mi < 8; mi++){
            int mloc = mi*16 + (g4 << 2);
            ushort4 o;
            o.x = f2bf(acc[mi][ni][0] + bv);
            o.y = f2bf(acc[mi][ni][1] + bv);
            o.z = f2bf(acc[mi][ni][2] + bv);
            o.w = f2bf(acc[mi][ni][3] + bv);
            *reinterpret_cast<ushort4*>(&u.vt[nl][mloc]) = o;   // 4 consecutive m at row nl
          }
        }
      }
      __syncthreads();
      #pragma unroll
      for (int c = 0; c < 8; c++){
        int idx = c*512 + tid;
        int nl = idx >> 4, ch = idx & 15;
        bf16x8 v = *reinterpret_cast<const bf16x8*>(&u.vt[nl][ch*8]);
        int gn = n0 + nl;
        int cc = gn & 1023, hh2 = cc >> 6, dd = cc & 63;
        int gm = m0 + p*128 + ch*8;
        bool isctx = gm >= BB*T;
        int rm = isctx ? gm - BB*T : gm;
        int bidx = rm >> 11, tt = rm & 2047;
        int j = isctx ? T + tt : tt;
        size_t bh2 = (size_t)bidx*H + hh2;
        *reinterpret_cast<bf16x8*>(vtbuf + (bh2*DH + dd)*L + j) = v;
      }
    }
  }
}

// ---------------- flash attention, split-KV x2: 32x32 MFMA, KVBLK=64, in-register P --------
// grid 1024 = 2 kv-chunks x 32 bh x 16 qt; 4 waves x 32 q = 128 q/block; LDS 32KB (dbuf)
// -> 4 blocks/CU, 16 waves/CU.  (r7-proven version)
__global__ __launch_bounds__(256, 4) void attn_kernel(const unsigned short* __restrict__ q,
      const unsigned short* __restrict__ kbuf, const unsigned short* __restrict__ vtbuf,
      unsigned short* __restrict__ obuf, float* __restrict__ mbuf, float* __restrict__ lbuf){
  // XCD swizzle: each XCD gets 8 bh x 1 chunk x 16 qt (4MB of K/V -> fits its L2)
  int hw = blockIdx.x;
  int wid = (hw & 7)*128 + (hw >> 3);
  int qt = wid & 15, bh = (wid >> 4) & 31, cb = wid >> 9;
  int hh = bh & 15, b = bh >> 4;
  int tid = threadIdx.x, lane = tid & 63, wv = tid >> 6;  // 4 waves
  int hi = lane >> 5, q32 = lane & 31;
  __shared__ unsigned short kt[2][64*64];
  __shared__ unsigned short vtt[2][64*64];
  size_t bhs = (size_t)b*H + hh;
  int qbase = qt*128 + wv*32;

  // Q fragments (B-operand): lane holds q-col = q32, k = d = ks*16 + hi*8 + j
  const unsigned short* qp = q + (bhs*T + qbase + q32)*DH + hi*8;
  bf16x8 qf[4];
  #pragma unroll
  for (int ks = 0; ks < 4; ks++)
    qf[ks] = *reinterpret_cast<const bf16x8*>(qp + ks*16);

  bf16x8 ones;
  #pragma unroll
  for (int j = 0; j < 8; j++) ones[j] = (__bf16)1.0f;

  f32x16 o_acc[2], l_vec;
  #pragma unroll
  for (int d = 0; d < 2; d++)
    #pragma unroll
    for (int i = 0; i < 16; i++) o_acc[d][i] = 0.f;
  #pragma unroll
  for (int i = 0; i < 16; i++) l_vec[i] = 0.f;
  float m_l = -1e30f;

  const char* kg = (const char*)(kbuf + bhs*(size_t)L*DH) + (size_t)cb*2048*128;
  const char* vg = (const char*)(vtbuf + bhs*(size_t)DH*L) + (size_t)cb*4096;

  // stage one 64-kv tile (16KB): K [64 kv][64 d], V [64 d][64 kv], chunk-swizzled
  #define STAGE(bufi, jt) { \
    _Pragma("unroll") \
    for (int c = 0; c < 2; c++){ \
      int idx = c*256 + tid; \
      int row = idx >> 3, c16 = idx & 7; \
      int sc16 = c16 ^ (row & 7); \
      gload_lds16(kg + (size_t)((jt)*64 + row)*128 + sc16*16, \
                  (char*)kt[bufi] + (c*256 + wv*64)*16); \
      gload_lds16(vg + (size_t)row*(L*2) + (jt)*128 + sc16*16, \
                  (char*)vtt[bufi] + (c*256 + wv*64)*16); \
    } }

  STAGE(0, 0);
  __syncthreads();

  for (int jt = 0; jt < 32; ++jt){
    int bufi = jt & 1;
    if (jt + 1 < 32) STAGE(bufi^1, jt+1);   // prefetch overlaps compute
    const char* kb = (const char*)kt[bufi];
    const char* vb = (const char*)vtt[bufi];

    // S^T[kv][q]: two 32-kv blocks, chained over 4 k-steps of 16
    f32x16 sc[2];
    #pragma unroll
    for (int t = 0; t < 2; t++)
      #pragma unroll
      for (int i = 0; i < 16; i++) sc[t][i] = 0.f;
    #pragma unroll
    for (int ks = 0; ks < 4; ks++){
      #pragma unroll
      for (int t = 0; t < 2; t++){
        int row = t*32 + q32;
        bf16x8 kf = *reinterpret_cast<const bf16x8*>(kb + row*128 + (((ks*2+hi) ^ (row&7))*16));
        sc[t] = __builtin_amdgcn_mfma_f32_32x32x16_bf16(kf, qf[ks], sc[t], 0,0,0);
      }
    }

    // tile max via v_max3 tree
    float rt[2];
    #pragma unroll
    for (int t = 0; t < 2; t++){
      float v0 = fmax3(sc[t][0],  sc[t][1],  sc[t][2]);
      float v1 = fmax3(sc[t][3],  sc[t][4],  sc[t][5]);
      float v2 = fmax3(sc[t][6],  sc[t][7],  sc[t][8]);
      float v3 = fmax3(sc[t][9],  sc[t][10], sc[t][11]);
      float v4 = fmax3(sc[t][12], sc[t][13], sc[t][14]);
      rt[t] = fmaxf(fmax3(v0, v1, v2), fmax3(v3, v4, sc[t][15]));
    }
    float tm = fmaxf(rt[0], rt[1]);

    // online softmax (exp2 domain), defer-max THR=8
    if (!__all(tm - m_l <= 8.0f)){
      float tmf = fmaxf(tm, __shfl_xor(tm, 32, 64));
      float mn = fmaxf(m_l, tmf);
      float alpha = __builtin_amdgcn_exp2f(m_l - mn);
      m_l = mn;
      #pragma unroll
      for (int d = 0; d < 2; d++)
        #pragma unroll
        for (int i = 0; i < 16; i++) o_acc[d][i] *= alpha;
      l_vec[0] *= alpha;   // only reg 0 is ever read; MFMA adds equally to all regs
    }
    #pragma unroll
    for (int t = 0; t < 2; t++)
      #pragma unroll
      for (int i = 0; i < 16; i++)
        sc[t][i] = __builtin_amdgcn_exp2f(sc[t][i] - m_l);

    // P^T -> B-fragments, in-register: 16 cvt_pk + 8 permlane32_swap
    bf16x8 pfrag[4];
    #pragma unroll
    for (int t = 0; t < 2; t++){
      #pragma unroll
      for (int half = 0; half < 2; half++){
        unsigned p01 = cvt_pk_bf16(sc[t][half*8+0], sc[t][half*8+1]);
        unsigned p23 = cvt_pk_bf16(sc[t][half*8+2], sc[t][half*8+3]);
        unsigned p45 = cvt_pk_bf16(sc[t][half*8+4], sc[t][half*8+5]);
        unsigned p67 = cvt_pk_bf16(sc[t][half*8+6], sc[t][half*8+7]);
        asm("v_permlane32_swap_b32 %0, %1" : "+v"(p01), "+v"(p45));
        asm("v_permlane32_swap_b32 %0, %1" : "+v"(p23), "+v"(p67));
        u32x4 w = (u32x4){p01, p23, p45, p67};
        pfrag[t*2 + half] = __builtin_bit_cast(bf16x8, w);
      }
    }

    // O^T[d][q] += V^T @ P^T ; l_vec += ones @ P^T
    #pragma unroll
    for (int ks = 0; ks < 4; ks++){
      #pragma unroll
      for (int d = 0; d < 2; d++){
        int row = d*32 + q32;
        bf16x8 vf = *reinterpret_cast<const bf16x8*>(vb + row*128 + (((ks*2+hi) ^ (row&7))*16));
        o_acc[d] = __builtin_amdgcn_mfma_f32_32x32x16_bf16(vf, pfrag[ks], o_acc[d], 0,0,0);
      }
      l_vec = __builtin_amdgcn_mfma_f32_32x32x16_bf16(ones, pfrag[ks], l_vec, 0,0,0);
    }
    __syncthreads();   // drains prefetch vmcnt + protects kt/vtt reuse
  }

  // write normalized partial O (bf16) + m/l
  float inv = 1.0f / l_vec[0];
  unsigned short* aop = obuf + (size_t)cb*BB*H*T*DH + ((size_t)bh*T + qbase + q32)*DH;
  #pragma unroll
  for (int d = 0; d < 2; d++)
    #pragma unroll
    for (int rg = 0; rg < 4; rg++){
      int d0 = d*32 + rg*8 + hi*4;
      ushort4 o;
      o.x = __builtin_bit_cast(unsigned short, (__bf16)(o_acc[d][rg*4+0]*inv));
      o.y = __builtin_bit_cast(unsigned short, (__bf16)(o_acc[d][rg*4+1]*inv));
      o.z = __builtin_bit_cast(unsigned short, (__bf16)(o_acc[d][rg*4+2]*inv));
      o.w = __builtin_bit_cast(unsigned short, (__bf16)(o_acc[d][rg*4+3]*inv));
      *reinterpret_cast<ushort4*>(aop + d0) = o;
    }
  if (hi == 0){
    size_t mi = ((size_t)cb*BB*H + bh)*T + qbase + q32;
    mbuf[mi] = m_l;
    lbuf[mi] = l_vec[0];
  }
}

// ---------------- combine the two KV-chunk partials ----------------
__global__ __launch_bounds__(256) void attn_combine(const unsigned short* __restrict__ obuf,
      const float* __restrict__ mbuf, const float* __restrict__ lbuf,
      unsigned short* __restrict__ ao){
  int gid = blockIdx.x*256 + threadIdx.x;
  int d8 = gid & 7;
  int qg = gid >> 3;            // bh*T + q
  int qq = qg & (T-1);
  int bh = qg >> 11;
  int b = bh >> 4, h = bh & 15;
  float m0 = mbuf[(size_t)qg];
  float m1 = mbuf[(size_t)BB*H*T + qg];
  float l0 = lbuf[(size_t)qg];
  float l1 = lbuf[(size_t)BB*H*T + qg];
  float mm = fmaxf(m0, m1);
  float w0 = l0 * __builtin_amdgcn_exp2f(m0 - mm);
  float w1 = l1 * __builtin_amdgcn_exp2f(m1 - mm);
  float inv = 1.0f / (w0 + w1);
  w0 *= inv; w1 *= inv;
  bf16x8 o0 = *reinterpret_cast<const bf16x8*>(obuf + (size_t)qg*DH + d8*8);
  bf16x8 o1 = *reinterpret_cast<const bf16x8*>(obuf + (size_t)BB*H*T*DH + (size_t)qg*DH + d8*8);
  bf16x8 res;
  #pragma unroll
  for (int j = 0; j < 8; j++)
    res[j] = (__bf16)(w0*(float)o0[j] + w1*(float)o1[j]);
  *reinterpret_cast<bf16x8*>(ao + ((size_t)b*T + qq)*DIM + h*DH + d8*8) = res;
}

// ---------------- out projection + bias + residual, BM=64 x BN=128 (512 blocks, 2/CU) ------
__global__ __launch_bounds__(256) void out_gemm(const unsigned short* __restrict__ A,
      const unsigned short* __restrict__ Bt, const float* __restrict__ bout,
      const float* __restrict__ xres, float* __restrict__ out){
  int n0 = blockIdx.x*128, m0 = blockIdx.y*64;
  __shared__ unsigned short at[2][64*32];
  __shared__ unsigned short btile[2][128*32];
  int tid = threadIdx.x, lane = tid & 63, wv = tid >> 6;
  int wm = (wv >> 1)*32, wn = (wv & 1)*64;   // wave tile 32x64
  f32x4 acc[2][4];
  #pragma unroll
  for (int i = 0; i < 2; i++)
    #pragma unroll
    for (int j = 0; j < 4; j++) acc[i][j] = (f32x4){0.f,0.f,0.f,0.f};

  #define OSTAGE(bufi, k0) { \
    { int row = tid >> 2, koff = (tid & 3)*16; \
      gload_lds16((const char*)A + ((size_t)(m0+row)*DIM + (k0))*2 + koff, \
                  (char*)at[bufi] + (wv*64)*16); } \
    _Pragma("unroll") \
    for (int c = 0; c < 2; c++){ \
      int idx = c*256 + tid; \
      int row = idx >> 2, koff = (idx & 3)*16; \
      gload_lds16((const char*)Bt + ((size_t)(n0+row)*DIM + (k0))*2 + koff, \
                  (char*)btile[bufi] + (c*256 + wv*64)*16); \
    } }

  OSTAGE(0, 0);
  __syncthreads();

  for (int kt = 0; kt < 32; kt++){
    int bufi = kt & 1;
    if (kt + 1 < 32) OSTAGE(bufi^1, (kt+1)*32);   // prefetch overlaps compute
    bf16x8 af[2], bfv[4];
    #pragma unroll
    for (int i = 0; i < 2; i++)
      af[i]  = *reinterpret_cast<const bf16x8*>((const char*)at[bufi] + (wm + i*16 + (lane&15))*64 + (lane>>4)*16);
    #pragma unroll
    for (int i = 0; i < 4; i++)
      bfv[i] = *reinterpret_cast<const bf16x8*>((const char*)btile[bufi] + (wn + i*16 + (lane&15))*64 + (lane>>4)*16);
    #pragma unroll
    for (int mi = 0; mi < 2; mi++)
      #pragma unroll
      for (int ni = 0; ni < 4; ni++)
        acc[mi][ni] = __builtin_amdgcn_mfma_f32_16x16x32_bf16(af[mi], bfv[ni], acc[mi][ni], 0,0,0);
    __syncthreads();   // drains prefetch vmcnt + protects buffer reuse
  }

  #pragma unroll
  for (int ni = 0; ni < 4; ni++){
    int gn = n0 + wn + ni*16 + (lane & 15);
    float bv = bout[gn];
    #pragma unroll
    for (int mi = 0; mi < 2; mi++){
      int gmb = m0 + wm + mi*16 + ((lane >> 4) << 2);
      #pragma unroll
      for (int r = 0; r < 4; r++){
        int gm = gmb + r;
        out[(size_t)gm*DIM + gn] = acc[mi][ni][r] + bv + xres[(size_t)gm*DIM + gn];
      }
    }
  }
}

extern "C" void kernel_launch(void* const* d_in, const int* in_sizes, int n_in,
                              void* d_out, int out_size, void* d_ws, size_t ws_size,
                              hipStream_t stream){
  const float* x    = (const float*)d_in[0];
  const float* ctx  = (const float*)d_in[1];
  const float* wqkv = (const float*)d_in[2];
  const float* bqkv = (const float*)d_in[3];
  const float* wout = (const float*)d_in[4];
  const float* bout = (const float*)d_in[5];
  const float* lng  = (const float*)d_in[6];
  const float* lnb  = (const float*)d_in[7];
  float* out = (float*)d_out;

  char* ws = (char*)d_ws;
  unsigned short* wqkvT  = (unsigned short*)ws; ws += (size_t)3072*1024*2;
  unsigned short* woutT  = (unsigned short*)ws; ws += (size_t)1024*1024*2;
  unsigned short* ln_all = (unsigned short*)ws; ws += (size_t)8192*1024*2;
  unsigned short* qbuf   = (unsigned short*)ws; ws += (size_t)BB*H*T*DH*2;
  unsigned short* kbuf   = (unsigned short*)ws; ws += (size_t)BB*H*L*DH*2;
  unsigned short* vtbuf  = (unsigned short*)ws; ws += (size_t)BB*H*DH*L*2;
  unsigned short* aobuf  = (unsigned short*)ws; ws += (size_t)BB*T*DIM*2;

  // dead-region reuse: obuf (2 x 8MB) = ln_all (16MB, dead after qkv_gemm);
  // mbuf/lbuf (0.5MB each) = wqkvT (6MB, dead after qkv_gemm)
  unsigned short* obuf = ln_all;
  float* mbuf = (float*)wqkvT;
  float* lbuf = mbuf + (size_t)2*BB*H*T;

  transpose_f32_bf16<<<dim3(3072/32, 1024/32), dim3(256), 0, stream>>>(wqkv, wqkvT, 1024, 3072);
  transpose_f32_bf16<<<dim3(1024/32, 1024/32), dim3(256), 0, stream>>>(wout, woutT, 1024, 1024);
  ln_kernel<<<dim3(8192), dim3(256), 0, stream>>>(x, ctx, lng, lnb, ln_all);
  qkv_gemm<<<dim3(320), dim3(512), 0, stream>>>(ln_all, wqkvT, bqkv, qbuf, kbuf, vtbuf);
  attn_kernel<<<dim3(1024), dim3(256), 0, stream>>>(qbuf, kbuf, vtbuf, obuf, mbuf, lbuf);
  attn_combine<<<dim3(BB*H*T*8/256), dim3(256), 0, stream>>>(obuf, mbuf, lbuf, aobuf);
  out_gemm<<<dim3(1024/128, 4096/64), dim3(256), 0, stream>>>(aobuf, woutT, bout, x, out);
}

// Round 17
// 211.363 us; speedup vs baseline: 1.0427x; 1.0427x over previous
//
#include <hip/hip_runtime.h>
#include <stdint.h>

#define H 16
#define DH 64
#define T 2048
#define SS 2048
#define L 4096
#define DIM 1024
#define BB 2

typedef __bf16 bf16x8 __attribute__((ext_vector_type(8)));
typedef float f32x4 __attribute__((ext_vector_type(4)));
typedef float f32x16 __attribute__((ext_vector_type(16)));
typedef unsigned u32x4 __attribute__((ext_vector_type(4)));

__device__ __forceinline__ unsigned short f2bf(float f){
  unsigned u = __builtin_bit_cast(unsigned, f);
  u += 0x7fff + ((u >> 16) & 1);
  return (unsigned short)(u >> 16);
}

__device__ __forceinline__ unsigned cvt_pk_bf16(float lo, float hi){
  unsigned r;
  asm("v_cvt_pk_bf16_f32 %0, %1, %2" : "=v"(r) : "v"(lo), "v"(hi));
  return r;
}

__device__ __forceinline__ float fmax3(float a, float b, float c){
  float r;
  asm("v_max3_f32 %0, %1, %2, %3" : "=v"(r) : "v"(a), "v"(b), "v"(c));
  return r;
}

__device__ __forceinline__ void gload_lds16(const void* g, void* l){
  void* gnc = const_cast<void*>(g);
  __builtin_amdgcn_global_load_lds((__attribute__((address_space(1))) void*)gnc,
                                   (__attribute__((address_space(3))) void*)l, 16, 0, 0);
}

// ---------------- LayerNorm (x rows then ctx rows) -> bf16 ----------------
__global__ __launch_bounds__(256) void ln_kernel(const float* __restrict__ x, const float* __restrict__ ctx,
                          const float* __restrict__ g, const float* __restrict__ b,
                          unsigned short* __restrict__ out){
  int row = blockIdx.x;
  int tid = threadIdx.x;
  const float* src = (row < BB*T) ? (x + (size_t)row*DIM) : (ctx + (size_t)(row - BB*T)*DIM);
  float4 v = reinterpret_cast<const float4*>(src)[tid];
  float s  = v.x + v.y + v.z + v.w;
  float s2 = v.x*v.x + v.y*v.y + v.z*v.z + v.w*v.w;
  #pragma unroll
  for (int off = 32; off > 0; off >>= 1){
    s  += __shfl_down(s,  off, 64);
    s2 += __shfl_down(s2, off, 64);
  }
  __shared__ float red[8];
  if ((tid & 63) == 0){ red[(tid>>6)*2] = s; red[(tid>>6)*2+1] = s2; }
  __syncthreads();
  s  = red[0] + red[2] + red[4] + red[6];
  s2 = red[1] + red[3] + red[5] + red[7];
  float mean = s * (1.0f/DIM);
  float var  = s2 * (1.0f/DIM) - mean*mean;
  float rstd = rsqrtf(var + 1e-5f);
  float4 gg = reinterpret_cast<const float4*>(g)[tid];
  float4 bv = reinterpret_cast<const float4*>(b)[tid];
  ushort4 o;
  o.x = f2bf((v.x-mean)*rstd*gg.x + bv.x);
  o.y = f2bf((v.y-mean)*rstd*gg.y + bv.y);
  o.z = f2bf((v.z-mean)*rstd*gg.z + bv.z);
  o.w = f2bf((v.w-mean)*rstd*gg.w + bv.w);
  reinterpret_cast<ushort4*>(out + (size_t)row*DIM)[tid] = o;
}

// ---------------- transpose fp32 [R][C] -> bf16 [C][R] ----------------
__global__ __launch_bounds__(256) void transpose_f32_bf16(const float* __restrict__ in,
                          unsigned short* __restrict__ out, int R, int C){
  __shared__ float tile[32][33];
  int c0 = blockIdx.x*32, r0 = blockIdx.y*32;
  int tx = threadIdx.x & 31, ty = threadIdx.x >> 5;
  #pragma unroll
  for (int k = 0; k < 4; k++)
    tile[ty + k*8][tx] = in[(size_t)(r0 + ty + k*8)*C + c0 + tx];
  __syncthreads();
  #pragma unroll
  for (int k = 0; k < 4; k++)
    out[(size_t)(c0 + ty + k*8)*R + r0 + tx] = f2bf(tile[tx][ty + k*8]);
}

// ---------------- QKV GEMM: all-resident static grid (1280 = 256 CU x 5 blocks) ------------
// LDS capped at 32KB (2-pass epilogue) + VGPR capped at 102 (launch_bounds(256,5)) -> all
// 1280 active tiles resident at once.  Static decode keeps xcd = g&7 == hardware round-robin
// XCD; m fastest -> B n-tile L2-hot (r12 locality).  [r16 lesson: coarse 8-phase without the
// exact counted-vmcnt choreography regresses; 2-phase is this kernel's validated optimum.]
__global__ __launch_bounds__(256, 5) void qkv_gemm(const unsigned short* __restrict__ A,
      const unsigned short* __restrict__ Bt, const float* __restrict__ bias,
      unsigned short* __restrict__ qbuf, unsigned short* __restrict__ kbuf,
      unsigned short* __restrict__ vtbuf){
  int g = blockIdx.x;
  int xcd = g & 7, a = g >> 3;                          // a in [0,160)
  int w = (a < 32) ? ((a >> 2)*8 + (a & 3)) : (a + 32); // active wid in [0,192)
  int mblk = ((w & 7) << 3) + xcd;                      // [0,64)
  int nblk = w >> 3;                                    // [0,24)
  int n0 = nblk*128, m0 = mblk*128;
  __shared__ union {
    struct { unsigned short at[2][128*32]; unsigned short bt[2][128*32]; } s;  // 32 KB
    unsigned short ct[64][136];    // [m-half][n] row-major (Q/K epilogue, 2 passes)
    unsigned short vt[128][72];    // [n][m-half] transposed (V epilogue, 2 passes)
  } u;
  int tid = threadIdx.x, lane = tid & 63, wv = tid >> 6;
  int wm = (wv >> 1)*64, wn = (wv & 1)*64;
  f32x4 acc[4][4];
  #pragma unroll
  for (int i = 0; i < 4; i++)
    #pragma unroll
    for (int j = 0; j < 4; j++) acc[i][j] = (f32x4){0.f,0.f,0.f,0.f};

  #define QSTAGE(bufi, k0) { \
    _Pragma("unroll") \
    for (int c = 0; c < 2; c++){ \
      int idx = c*256 + tid; \
      int row = idx >> 2, koff = (idx & 3)*16; \
      gload_lds16((const char*)A  + ((size_t)(m0+row)*DIM + (k0))*2 + koff, \
                  (char*)u.s.at[bufi] + (c*256 + wv*64)*16); \
      gload_lds16((const char*)Bt + ((size_t)(n0+row)*DIM + (k0))*2 + koff, \
                  (char*)u.s.bt[bufi] + (c*256 + wv*64)*16); \
    } }

  QSTAGE(0, 0);
  __syncthreads();

  for (int kt = 0; kt < 32; kt++){
    int bufi = kt & 1;
    if (kt + 1 < 32) QSTAGE(bufi^1, (kt+1)*32);   // prefetch overlaps compute
    bf16x8 af[4], bfv[4];
    #pragma unroll
    for (int i = 0; i < 4; i++){
      af[i]  = *reinterpret_cast<const bf16x8*>((const char*)u.s.at[bufi] + (wm + i*16 + (lane&15))*64 + (lane>>4)*16);
      bfv[i] = *reinterpret_cast<const bf16x8*>((const char*)u.s.bt[bufi] + (wn + i*16 + (lane&15))*64 + (lane>>4)*16);
    }
    #pragma unroll
    for (int mi = 0; mi < 4; mi++)
      #pragma unroll
      for (int ni = 0; ni < 4; ni++)
        acc[mi][ni] = __builtin_amdgcn_mfma_f32_16x16x32_bf16(af[mi], bfv[ni], acc[mi][ni], 0,0,0);
    __syncthreads();   // drains prefetch vmcnt + protects buffer reuse
  }

  int sec = n0 >> 10;   // 0=Q, 1=K, 2=V
  if (sec < 2){
    float scale = (sec == 0) ? 0.18033688f : 1.0f;  // 0.125*log2(e) for Q
    #pragma unroll
    for (int p = 0; p < 2; p++){
      __syncthreads();
      if ((wv >> 1) == p){        // waves owning m rows [p*64, p*64+64)
        #pragma unroll
        for (int ni = 0; ni < 4; ni++){
          int nl = wn + ni*16 + (lane & 15);
          float bv = bias[n0 + nl];
          #pragma unroll
          for (int mi = 0; mi < 4; mi++){
            int mloc = mi*16 + ((lane >> 4) << 2);
            #pragma unroll
            for (int r = 0; r < 4; r++)
              u.ct[mloc + r][nl] = f2bf((acc[mi][ni][r] + bv)*scale);
          }
        }
      }
      __syncthreads();
      #pragma unroll
      for (int c = 0; c < 4; c++){
        int idx = c*256 + tid;
        int row = idx >> 4, ch = idx & 15;
        bf16x8 v = *reinterpret_cast<const bf16x8*>(&u.ct[row][ch*8]);
        int gm = m0 + p*64 + row, gn = n0 + ch*8;
        int cc = gn & 1023, hh2 = cc >> 6, d = cc & 63;
        bool isctx = gm >= BB*T;
        int rm = isctx ? gm - BB*T : gm;
        int bidx = rm >> 11, tt = rm & 2047;
        size_t bh2 = (size_t)bidx*H + hh2;
        if (sec == 0){
          *reinterpret_cast<bf16x8*>(qbuf + (bh2*T + tt)*DH + d) = v;   // Q tiles never ctx
        } else {
          int j = isctx ? T + tt : tt;
          *reinterpret_cast<bf16x8*>(kbuf + (bh2*L + j)*DH + d) = v;
        }
      }
    }
  } else {
    #pragma unroll
    for (int p = 0; p < 2; p++){
      __syncthreads();
      if ((wv >> 1) == p){
        #pragma unroll
        for (int ni = 0; ni < 4; ni++){
          int nl = wn + ni*16 + (lane & 15);
          float bv = bias[n0 + nl];
          #pragma unroll
          for (int mi = 0; mi < 4; mi++){
            int mloc = mi*16 + ((lane >> 4) << 2);
            ushort4 o;
            o.x = f2bf(acc[mi][ni][0] + bv);
            o.y = f2bf(acc[mi][ni][1] + bv);
            o.z = f2bf(acc[mi][ni][2] + bv);
            o.w = f2bf(acc[mi][ni][3] + bv);
            *reinterpret_cast<ushort4*>(&u.vt[nl][mloc]) = o;   // 4 consecutive m at row nl
          }
        }
      }
      __syncthreads();
      #pragma unroll
      for (int c = 0; c < 4; c++){
        int idx = c*256 + tid;
        int nl = idx >> 3, ch = idx & 7;
        bf16x8 v = *reinterpret_cast<const bf16x8*>(&u.vt[nl][ch*8]);
        int gn = n0 + nl;
        int cc = gn & 1023, hh2 = cc >> 6, d = cc & 63;
        int gm = m0 + p*64 + ch*8;
        bool isctx = gm >= BB*T;
        int rm = isctx ? gm - BB*T : gm;
        int bidx = rm >> 11, tt = rm & 2047;
        int j = isctx ? T + tt : tt;
        size_t bh2 = (size_t)bidx*H + hh2;
        *reinterpret_cast<bf16x8*>(vtbuf + (bh2*DH + d)*L + j) = v;
      }
    }
  }
}

// ---------------- flash attention, split-KV x2: 32x32 MFMA, KVBLK=64, in-register P --------
// grid 1024 = 2 kv-chunks x 32 bh x 16 qt; 4 waves x 32 q = 128 q/block; LDS 32KB (dbuf)
// -> 4 blocks/CU, 16 waves/CU.  (r7-proven version)
__global__ __launch_bounds__(256, 4) void attn_kernel(const unsigned short* __restrict__ q,
      const unsigned short* __restrict__ kbuf, const unsigned short* __restrict__ vtbuf,
      unsigned short* __restrict__ obuf, float* __restrict__ mbuf, float* __restrict__ lbuf){
  // XCD swizzle: each XCD gets 8 bh x 1 chunk x 16 qt (4MB of K/V -> fits its L2)
  int hw = blockIdx.x;
  int wid = (hw & 7)*128 + (hw >> 3);
  int qt = wid & 15, bh = (wid >> 4) & 31, cb = wid >> 9;
  int hh = bh & 15, b = bh >> 4;
  int tid = threadIdx.x, lane = tid & 63, wv = tid >> 6;  // 4 waves
  int hi = lane >> 5, q32 = lane & 31;
  __shared__ unsigned short kt[2][64*64];
  __shared__ unsigned short vtt[2][64*64];
  size_t bhs = (size_t)b*H + hh;
  int qbase = qt*128 + wv*32;

  // Q fragments (B-operand): lane holds q-col = q32, k = d = ks*16 + hi*8 + j
  const unsigned short* qp = q + (bhs*T + qbase + q32)*DH + hi*8;
  bf16x8 qf[4];
  #pragma unroll
  for (int ks = 0; ks < 4; ks++)
    qf[ks] = *reinterpret_cast<const bf16x8*>(qp + ks*16);

  bf16x8 ones;
  #pragma unroll
  for (int j = 0; j < 8; j++) ones[j] = (__bf16)1.0f;

  f32x16 o_acc[2], l_vec;
  #pragma unroll
  for (int d = 0; d < 2; d++)
    #pragma unroll
    for (int i = 0; i < 16; i++) o_acc[d][i] = 0.f;
  #pragma unroll
  for (int i = 0; i < 16; i++) l_vec[i] = 0.f;
  float m_l = -1e30f;

  const char* kg = (const char*)(kbuf + bhs*(size_t)L*DH) + (size_t)cb*2048*128;
  const char* vg = (const char*)(vtbuf + bhs*(size_t)DH*L) + (size_t)cb*4096;

  // stage one 64-kv tile (16KB): K [64 kv][64 d], V [64 d][64 kv], chunk-swizzled
  #define STAGE(bufi, jt) { \
    _Pragma("unroll") \
    for (int c = 0; c < 2; c++){ \
      int idx = c*256 + tid; \
      int row = idx >> 3, c16 = idx & 7; \
      int sc16 = c16 ^ (row & 7); \
      gload_lds16(kg + (size_t)((jt)*64 + row)*128 + sc16*16, \
                  (char*)kt[bufi] + (c*256 + wv*64)*16); \
      gload_lds16(vg + (size_t)row*(L*2) + (jt)*128 + sc16*16, \
                  (char*)vtt[bufi] + (c*256 + wv*64)*16); \
    } }

  STAGE(0, 0);
  __syncthreads();

  for (int jt = 0; jt < 32; ++jt){
    int bufi = jt & 1;
    if (jt + 1 < 32) STAGE(bufi^1, jt+1);   // prefetch overlaps compute
    const char* kb = (const char*)kt[bufi];
    const char* vb = (const char*)vtt[bufi];

    // S^T[kv][q]: two 32-kv blocks, chained over 4 k-steps of 16
    f32x16 sc[2];
    #pragma unroll
    for (int t = 0; t < 2; t++)
      #pragma unroll
      for (int i = 0; i < 16; i++) sc[t][i] = 0.f;
    #pragma unroll
    for (int ks = 0; ks < 4; ks++){
      #pragma unroll
      for (int t = 0; t < 2; t++){
        int row = t*32 + q32;
        bf16x8 kf = *reinterpret_cast<const bf16x8*>(kb + row*128 + (((ks*2+hi) ^ (row&7))*16));
        sc[t] = __builtin_amdgcn_mfma_f32_32x32x16_bf16(kf, qf[ks], sc[t], 0,0,0);
      }
    }

    // tile max via v_max3 tree
    float rt[2];
    #pragma unroll
    for (int t = 0; t < 2; t++){
      float v0 = fmax3(sc[t][0],  sc[t][1],  sc[t][2]);
      float v1 = fmax3(sc[t][3],  sc[t][4],  sc[t][5]);
      float v2 = fmax3(sc[t][6],  sc[t][7],  sc[t][8]);
      float v3 = fmax3(sc[t][9],  sc[t][10], sc[t][11]);
      float v4 = fmax3(sc[t][12], sc[t][13], sc[t][14]);
      rt[t] = fmaxf(fmax3(v0, v1, v2), fmax3(v3, v4, sc[t][15]));
    }
    float tm = fmaxf(rt[0], rt[1]);

    // online softmax (exp2 domain), defer-max THR=8
    if (!__all(tm - m_l <= 8.0f)){
      float tmf = fmaxf(tm, __shfl_xor(tm, 32, 64));
      float mn = fmaxf(m_l, tmf);
      float alpha = __builtin_amdgcn_exp2f(m_l - mn);
      m_l = mn;
      #pragma unroll
      for (int d = 0; d < 2; d++)
        #pragma unroll
        for (int i = 0; i < 16; i++) o_acc[d][i] *= alpha;
      l_vec[0] *= alpha;   // only reg 0 is ever read; MFMA adds equally to all regs
    }
    #pragma unroll
    for (int t = 0; t < 2; t++)
      #pragma unroll
      for (int i = 0; i < 16; i++)
        sc[t][i] = __builtin_amdgcn_exp2f(sc[t][i] - m_l);

    // P^T -> B-fragments, in-register: 16 cvt_pk + 8 permlane32_swap
    bf16x8 pfrag[4];
    #pragma unroll
    for (int t = 0; t < 2; t++){
      #pragma unroll
      for (int half = 0; half < 2; half++){
        unsigned p01 = cvt_pk_bf16(sc[t][half*8+0], sc[t][half*8+1]);
        unsigned p23 = cvt_pk_bf16(sc[t][half*8+2], sc[t][half*8+3]);
        unsigned p45 = cvt_pk_bf16(sc[t][half*8+4], sc[t][half*8+5]);
        unsigned p67 = cvt_pk_bf16(sc[t][half*8+6], sc[t][half*8+7]);
        asm("v_permlane32_swap_b32 %0, %1" : "+v"(p01), "+v"(p45));
        asm("v_permlane32_swap_b32 %0, %1" : "+v"(p23), "+v"(p67));
        u32x4 w = (u32x4){p01, p23, p45, p67};
        pfrag[t*2 + half] = __builtin_bit_cast(bf16x8, w);
      }
    }

    // O^T[d][q] += V^T @ P^T ; l_vec += ones @ P^T
    #pragma unroll
    for (int ks = 0; ks < 4; ks++){
      #pragma unroll
      for (int d = 0; d < 2; d++){
        int row = d*32 + q32;
        bf16x8 vf = *reinterpret_cast<const bf16x8*>(vb + row*128 + (((ks*2+hi) ^ (row&7))*16));
        o_acc[d] = __builtin_amdgcn_mfma_f32_32x32x16_bf16(vf, pfrag[ks], o_acc[d], 0,0,0);
      }
      l_vec = __builtin_amdgcn_mfma_f32_32x32x16_bf16(ones, pfrag[ks], l_vec, 0,0,0);
    }
    __syncthreads();   // drains prefetch vmcnt + protects kt/vtt reuse
  }

  // write normalized partial O (bf16) + m/l
  float inv = 1.0f / l_vec[0];
  unsigned short* aop = obuf + (size_t)cb*BB*H*T*DH + ((size_t)bh*T + qbase + q32)*DH;
  #pragma unroll
  for (int d = 0; d < 2; d++)
    #pragma unroll
    for (int rg = 0; rg < 4; rg++){
      int d0 = d*32 + rg*8 + hi*4;
      ushort4 o;
      o.x = __builtin_bit_cast(unsigned short, (__bf16)(o_acc[d][rg*4+0]*inv));
      o.y = __builtin_bit_cast(unsigned short, (__bf16)(o_acc[d][rg*4+1]*inv));
      o.z = __builtin_bit_cast(unsigned short, (__bf16)(o_acc[d][rg*4+2]*inv));
      o.w = __builtin_bit_cast(unsigned short, (__bf16)(o_acc[d][rg*4+3]*inv));
      *reinterpret_cast<ushort4*>(aop + d0) = o;
    }
  if (hi == 0){
    size_t mi = ((size_t)cb*BB*H + bh)*T + qbase + q32;
    mbuf[mi] = m_l;
    lbuf[mi] = l_vec[0];
  }
}

// ---------------- combine the two KV-chunk partials ----------------
__global__ __launch_bounds__(256) void attn_combine(const unsigned short* __restrict__ obuf,
      const float* __restrict__ mbuf, const float* __restrict__ lbuf,
      unsigned short* __restrict__ ao){
  int gid = blockIdx.x*256 + threadIdx.x;
  int d8 = gid & 7;
  int qg = gid >> 3;            // bh*T + q
  int qq = qg & (T-1);
  int bh = qg >> 11;
  int b = bh >> 4, h = bh & 15;
  float m0 = mbuf[(size_t)qg];
  float m1 = mbuf[(size_t)BB*H*T + qg];
  float l0 = lbuf[(size_t)qg];
  float l1 = lbuf[(size_t)BB*H*T + qg];
  float mm = fmaxf(m0, m1);
  float w0 = l0 * __builtin_amdgcn_exp2f(m0 - mm);
  float w1 = l1 * __builtin_amdgcn_exp2f(m1 - mm);
  float inv = 1.0f / (w0 + w1);
  w0 *= inv; w1 *= inv;
  bf16x8 o0 = *reinterpret_cast<const bf16x8*>(obuf + (size_t)qg*DH + d8*8);
  bf16x8 o1 = *reinterpret_cast<const bf16x8*>(obuf + (size_t)BB*H*T*DH + (size_t)qg*DH + d8*8);
  bf16x8 res;
  #pragma unroll
  for (int j = 0; j < 8; j++)
    res[j] = (__bf16)(w0*(float)o0[j] + w1*(float)o1[j]);
  *reinterpret_cast<bf16x8*>(ao + ((size_t)b*T + qq)*DIM + h*DH + d8*8) = res;
}

// ---------------- out projection + bias + residual, BM=64 x BN=128 (512 blocks, 2/CU) ------
__global__ __launch_bounds__(256) void out_gemm(const unsigned short* __restrict__ A,
      const unsigned short* __restrict__ Bt, const float* __restrict__ bout,
      const float* __restrict__ xres, float* __restrict__ out){
  int n0 = blockIdx.x*128, m0 = blockIdx.y*64;
  __shared__ unsigned short at[2][64*32];
  __shared__ unsigned short btile[2][128*32];
  int tid = threadIdx.x, lane = tid & 63, wv = tid >> 6;
  int wm = (wv >> 1)*32, wn = (wv & 1)*64;   // wave tile 32x64
  f32x4 acc[2][4];
  #pragma unroll
  for (int i = 0; i < 2; i++)
    #pragma unroll
    for (int j = 0; j < 4; j++) acc[i][j] = (f32x4){0.f,0.f,0.f,0.f};

  #define OSTAGE(bufi, k0) { \
    { int row = tid >> 2, koff = (tid & 3)*16; \
      gload_lds16((const char*)A + ((size_t)(m0+row)*DIM + (k0))*2 + koff, \
                  (char*)at[bufi] + (wv*64)*16); } \
    _Pragma("unroll") \
    for (int c = 0; c < 2; c++){ \
      int idx = c*256 + tid; \
      int row = idx >> 2, koff = (idx & 3)*16; \
      gload_lds16((const char*)Bt + ((size_t)(n0+row)*DIM + (k0))*2 + koff, \
                  (char*)btile[bufi] + (c*256 + wv*64)*16); \
    } }

  OSTAGE(0, 0);
  __syncthreads();

  for (int kt = 0; kt < 32; kt++){
    int bufi = kt & 1;
    if (kt + 1 < 32) OSTAGE(bufi^1, (kt+1)*32);   // prefetch overlaps compute
    bf16x8 af[2], bfv[4];
    #pragma unroll
    for (int i = 0; i < 2; i++)
      af[i]  = *reinterpret_cast<const bf16x8*>((const char*)at[bufi] + (wm + i*16 + (lane&15))*64 + (lane>>4)*16);
    #pragma unroll
    for (int i = 0; i < 4; i++)
      bfv[i] = *reinterpret_cast<const bf16x8*>((const char*)btile[bufi] + (wn + i*16 + (lane&15))*64 + (lane>>4)*16);
    #pragma unroll
    for (int mi = 0; mi < 2; mi++)
      #pragma unroll
      for (int ni = 0; ni < 4; ni++)
        acc[mi][ni] = __builtin_amdgcn_mfma_f32_16x16x32_bf16(af[mi], bfv[ni], acc[mi][ni], 0,0,0);
    __syncthreads();   // drains prefetch vmcnt + protects buffer reuse
  }

  #pragma unroll
  for (int ni = 0; ni < 4; ni++){
    int gn = n0 + wn + ni*16 + (lane & 15);
    float bv = bout[gn];
    #pragma unroll
    for (int mi = 0; mi < 2; mi++){
      int gmb = m0 + wm + mi*16 + ((lane >> 4) << 2);
      #pragma unroll
      for (int r = 0; r < 4; r++){
        int gm = gmb + r;
        out[(size_t)gm*DIM + gn] = acc[mi][ni][r] + bv + xres[(size_t)gm*DIM + gn];
      }
    }
  }
}

extern "C" void kernel_launch(void* const* d_in, const int* in_sizes, int n_in,
                              void* d_out, int out_size, void* d_ws, size_t ws_size,
                              hipStream_t stream){
  const float* x    = (const float*)d_in[0];
  const float* ctx  = (const float*)d_in[1];
  const float* wqkv = (const float*)d_in[2];
  const float* bqkv = (const float*)d_in[3];
  const float* wout = (const float*)d_in[4];
  const float* bout = (const float*)d_in[5];
  const float* lng  = (const float*)d_in[6];
  const float* lnb  = (const float*)d_in[7];
  float* out = (float*)d_out;

  char* ws = (char*)d_ws;
  unsigned short* wqkvT  = (unsigned short*)ws; ws += (size_t)3072*1024*2;
  unsigned short* woutT  = (unsigned short*)ws; ws += (size_t)1024*1024*2;
  unsigned short* ln_all = (unsigned short*)ws; ws += (size_t)8192*1024*2;
  unsigned short* qbuf   = (unsigned short*)ws; ws += (size_t)BB*H*T*DH*2;
  unsigned short* kbuf   = (unsigned short*)ws; ws += (size_t)BB*H*L*DH*2;
  unsigned short* vtbuf  = (unsigned short*)ws; ws += (size_t)BB*H*DH*L*2;
  unsigned short* aobuf  = (unsigned short*)ws; ws += (size_t)BB*T*DIM*2;

  // dead-region reuse: obuf (2 x 8MB) = ln_all (16MB, dead after qkv_gemm);
  // mbuf/lbuf (0.5MB each) = wqkvT (6MB, dead after qkv_gemm)
  unsigned short* obuf = ln_all;
  float* mbuf = (float*)wqkvT;
  float* lbuf = mbuf + (size_t)2*BB*H*T;

  transpose_f32_bf16<<<dim3(3072/32, 1024/32), dim3(256), 0, stream>>>(wqkv, wqkvT, 1024, 3072);
  transpose_f32_bf16<<<dim3(1024/32, 1024/32), dim3(256), 0, stream>>>(wout, woutT, 1024, 1024);
  ln_kernel<<<dim3(8192), dim3(256), 0, stream>>>(x, ctx, lng, lnb, ln_all);
  qkv_gemm<<<dim3(1280), dim3(256), 0, stream>>>(ln_all, wqkvT, bqkv, qbuf, kbuf, vtbuf);
  attn_kernel<<<dim3(1024), dim3(256), 0, stream>>>(qbuf, kbuf, vtbuf, obuf, mbuf, lbuf);
  attn_combine<<<dim3(BB*H*T*8/256), dim3(256), 0, stream>>>(obuf, mbuf, lbuf, aobuf);
  out_gemm<<<dim3(1024/128, 4096/64), dim3(256), 0, stream>>>(aobuf, woutT, bout, x, out);
}